// Round 9
// baseline (701.057 us; speedup 1.0000x reference)
//
#include <hip/hip_runtime.h>
#include <hip/hip_bf16.h>

// R9 ABLATION ROUND. Real pipeline (REP=1, correct outputs) + 5 qkv ablation clones with
// DISTINCT KERNEL NAMES writing to scratch -> each gets its own rocprof row. Flags prune
// phases: STAGE (global_load_lds+vmcnt), READ (ds_read+lgkm), MFMA. Keep-alive asm where
// needed (rule #17). REPs sized so every ablation dispatch > 44.9us fill rows -> top-5 table
// = ablation table. Base kernel = R7/R8 (passed, conflict-fixed).

typedef short short8 __attribute__((ext_vector_type(8)));
typedef float f32x4 __attribute__((ext_vector_type(4)));

__device__ __forceinline__ unsigned short f2b(float f) {
    unsigned int x;
    __builtin_memcpy(&x, &f, 4);
    unsigned int r = x + 0x7FFF + ((x >> 16) & 1);  // RNE
    return (unsigned short)(r >> 16);
}

__device__ __forceinline__ unsigned int pk2(float a, float b) {
    __hip_bfloat162 h = __float22bfloat162_rn(make_float2(a, b));
    unsigned int u;
    __builtin_memcpy(&u, &h, 4);
    return u;
}

__device__ __forceinline__ void load_lds16(const unsigned short* g, unsigned short* l) {
    __builtin_amdgcn_global_load_lds(
        (const __attribute__((address_space(1))) unsigned int*)g,
        (__attribute__((address_space(3))) unsigned int*)l, 16, 0, 0);
}

// ---------------- prep: xcast (blocks 0..4095) + W transposes ----------------
__global__ __launch_bounds__(256) void prep(const float* __restrict__ x, unsigned int* __restrict__ xb,
                                            const float* __restrict__ wA, unsigned short* __restrict__ wtA,
                                            const float* __restrict__ wP, unsigned short* __restrict__ wtP) {
    const int bx = blockIdx.x, tid = threadIdx.x;
    if (bx < 4096) {
        int i = (bx * 256 + tid) * 4;
        float4 f = *(const float4*)(x + i);
        uint2 p;
        p.x = (unsigned int)f2b(f.x) | ((unsigned int)f2b(f.y) << 16);
        p.y = (unsigned int)f2b(f.z) | ((unsigned int)f2b(f.w) << 16);
        *(uint2*)(xb + i / 2) = p;
        return;
    }
    __shared__ unsigned short t[32][33];
    const float* in;
    unsigned short* out;
    int R, C, gx, gy, oc0;
    if (bx < 7168) {
        int i = bx - 4096; gx = i % 96; gy = i / 96; in = wA; out = wtA; R = 1024; C = 3072;
        int c0 = gx * 32;
        oc0 = ((c0 >> 6) & 15) * 192 + (c0 >> 10) * 64 + (c0 & 63);
    } else {
        int i = bx - 7168; gx = i % 32; gy = i / 32; in = wP; out = wtP; R = 1024; C = 1024;
        oc0 = gx * 32;
    }
    const int tx = tid & 31, ty = tid >> 5;
    const int c0 = gx * 32, r0 = gy * 32;
#pragma unroll
    for (int i = 0; i < 4; i++)
        t[ty + i * 8][tx] = f2b(in[(r0 + ty + i * 8) * C + c0 + tx]);
    __syncthreads();
#pragma unroll
    for (int i = 0; i < 4; i++)
        out[(oc0 + ty + i * 8) * R + r0 + tx] = t[tx][ty + i * 8];
}

// ---------------- QKV body macro: R7 structure with phase flags ----------------
#define QKV_KERNEL(NAME, REPN, DO_STAGE, DO_READ, DO_MFMA)                                        \
__global__ __launch_bounds__(256, 2) void NAME(const unsigned short* __restrict__ X,              \
                                               const unsigned short* __restrict__ WT,             \
                                               const float* __restrict__ bias,                    \
                                               unsigned short* __restrict__ Qo,                   \
                                               unsigned short* __restrict__ Ko,                   \
                                               unsigned short* __restrict__ Vt) {                 \
    __shared__ __align__(16) unsigned short SM[40960];                                            \
    unsigned short* Al = SM;                                                                      \
    unsigned short* Bl = SM + 16384;                                                              \
    const int tid = threadIdx.x;                                                                  \
    const int l = tid & 63, l15 = l & 15, quad = (tid & 63) >> 4;                                 \
    const int w = tid >> 6;                                                                       \
    const int wm = w >> 1, wn = w & 1;                                                            \
    const int fid = blockIdx.x + (blockIdx.y << 4);                                               \
    const int xcd = fid & 7, j8 = fid >> 3;                                                       \
    const int by = ((xcd >> 1) << 3) + (j8 >> 3);                                                 \
    const int bx = ((xcd & 1) << 3) + (j8 & 7);                                                   \
    const int m0 = by * 128, n0 = bx * 192, hx = bx;                                              \
    const int trow = tid >> 2;                                                                    \
    const int ch = (tid & 3) ^ ((tid >> 3) & 3);                                                  \
    const unsigned short* Asrc = X + (size_t)(m0 + trow) * 1024 + ch * 8;                         \
    const unsigned short* Bsrc = WT + (size_t)(n0 + trow) * 1024 + ch * 8;                        \
    const int koff = (quad ^ ((l15 >> 1) & 3)) << 3;                                              \
    auto stageA = [&](int buf, int k0) {                                                          \
        _Pragma("unroll") for (int u = 0; u < 2; ++u)                                             \
            load_lds16(Asrc + u * 65536 + k0, Al + buf * 4096 + u * 2048 + tid * 8);              \
    };                                                                                            \
    auto stageB = [&](int buf, int k0) {                                                          \
        _Pragma("unroll") for (int u = 0; u < 3; ++u)                                             \
            load_lds16(Bsrc + u * 65536 + k0, Bl + buf * 6144 + u * 2048 + tid * 8);              \
    };                                                                                            \
    const int b = m0 >> 11, sbase = m0 & 2047;                                                    \
    short8 af[4] = {}, bf[6] = {};                                                                \
    f32x4 acc[4][6];                                                                              \
    for (int rep = 0; rep < (REPN); ++rep) {                                                      \
        _Pragma("unroll") for (int mt = 0; mt < 4; ++mt)                                          \
            _Pragma("unroll") for (int nt = 0; nt < 6; ++nt)                                      \
                acc[mt][nt] = (f32x4){0.f, 0.f, 0.f, 0.f};                                        \
        if (DO_STAGE) {                                                                           \
            stageA(0, 0); stageB(0, 0);                                                           \
            stageA(1, 32); stageB(1, 32);                                                         \
            stageA(2, 64); stageB(2, 64);                                                         \
        }                                                                                         \
        _Pragma("unroll 1") for (int t = 0; t < 32; ++t) {                                        \
            const int c = t & 3;                                                                  \
            asm volatile("s_barrier" ::: "memory");                                               \
            if (DO_STAGE) {                                                                       \
                if (t < 29) {                                                                     \
                    const int kn = (t + 3) * 32;                                                  \
                    stageA((t + 3) & 3, kn);                                                      \
                    stageB((t + 3) & 3, kn);                                                      \
                    asm volatile("s_waitcnt vmcnt(15)" ::: "memory");                             \
                } else if (t == 29) {                                                             \
                    asm volatile("s_waitcnt vmcnt(10)" ::: "memory");                             \
                } else if (t == 30) {                                                             \
                    asm volatile("s_waitcnt vmcnt(5)" ::: "memory");                              \
                } else {                                                                          \
                    asm volatile("s_waitcnt vmcnt(0)" ::: "memory");                              \
                }                                                                                 \
            }                                                                                     \
            if (DO_READ) {                                                                        \
                const unsigned short* Ab = Al + c * 4096 + (wm * 64 + l15) * 32 + koff;           \
                const unsigned short* Bb = Bl + c * 6144 + (wn * 96 + l15) * 32 + koff;           \
                _Pragma("unroll") for (int mt = 0; mt < 4; ++mt)                                  \
                    af[mt] = *(const short8*)(Ab + mt * 512);                                     \
                _Pragma("unroll") for (int nt = 0; nt < 6; ++nt)                                  \
                    bf[nt] = *(const short8*)(Bb + nt * 512);                                     \
                asm volatile("s_waitcnt lgkmcnt(0)" ::: "memory");                                \
            }                                                                                     \
            __builtin_amdgcn_sched_barrier(0);                                                    \
            if (DO_MFMA) {                                                                        \
                __builtin_amdgcn_s_setprio(1);                                                    \
                _Pragma("unroll") for (int mt = 0; mt < 4; ++mt)                                  \
                    _Pragma("unroll") for (int nt = 0; nt < 6; ++nt)                              \
                        acc[mt][nt] = __builtin_amdgcn_mfma_f32_16x16x32_bf16(af[mt], bf[nt],     \
                                                                              acc[mt][nt], 0, 0, 0); \
                __builtin_amdgcn_s_setprio(0);                                                    \
            } else if (DO_READ) {                                                                 \
                asm volatile("" : "+v"(af[0]), "+v"(af[1]), "+v"(af[2]), "+v"(af[3]),             \
                                  "+v"(bf[0]), "+v"(bf[1]), "+v"(bf[2]), "+v"(bf[3]),             \
                                  "+v"(bf[4]), "+v"(bf[5]));                                      \
            }                                                                                     \
        }                                                                                         \
        __syncthreads();                                                                          \
        _Pragma("unroll") for (int nt = 0; nt < 6; ++nt) {                                        \
            const int f = wn * 96 + nt * 16;                                                      \
            const int type = f >> 6, d0 = f & 63;                                                 \
            const float bvv = bias[type * 1024 + hx * 64 + d0 + l15];                             \
            if (type < 2) {                                                                       \
                const float scale = type ? 0.125f : 1.0f;                                         \
                unsigned short* dst = type ? Ko : Qo;                                             \
                _Pragma("unroll") for (int mt = 0; mt < 4; ++mt)                                  \
                    _Pragma("unroll") for (int r = 0; r < 4; ++r) {                               \
                        int m = m0 + wm * 64 + mt * 16 + quad * 4 + r;                            \
                        dst[(((size_t)(b * 16 + hx)) * 2048 + (m & 2047)) * 64 + d0 + l15] =      \
                            f2b((acc[mt][nt][r] + bvv) * scale);                                  \
                    }                                                                             \
            } else {                                                                              \
                const int d = d0 + l15;                                                           \
                _Pragma("unroll") for (int mt = 0; mt < 4; ++mt) {                                \
                    int mloc = wm * 64 + mt * 16 + quad * 4;                                      \
                    uint2 u;                                                                      \
                    u.x = pk2(acc[mt][nt][0] + bvv, acc[mt][nt][1] + bvv);                        \
                    u.y = pk2(acc[mt][nt][2] + bvv, acc[mt][nt][3] + bvv);                        \
                    *(uint2*)&SM[d * 136 + mloc] = u;                                             \
                }                                                                                 \
            }                                                                                     \
        }                                                                                         \
        __syncthreads();                                                                          \
        {                                                                                         \
            const int d = tid >> 2, mseg = (tid & 3) * 32;                                        \
            size_t gb = ((size_t)((b * 16 + hx) * 64 + d)) * 2048 + sbase + mseg;                 \
            _Pragma("unroll") for (int q = 0; q < 4; ++q)                                         \
                *(uint4*)(Vt + gb + q * 8) = *(const uint4*)&SM[d * 136 + mseg + q * 8];          \
        }                                                                                         \
        __syncthreads();                                                                          \
    }                                                                                             \
}

QKV_KERNEL(qkv_gemm,      1,  1, 1, 1)   // real outputs
QKV_KERNEL(qkv_ab_full,   3,  1, 1, 1)   // scratch: full loop (validates scratch neutrality)
QKV_KERNEL(qkv_ab_nodma,  4,  0, 1, 1)   // scratch: no global_load_lds / vmcnt traffic
QKV_KERNEL(qkv_ab_nordd,  4,  1, 0, 1)   // scratch: no ds_read / lgkm (MFMA on zeros)
QKV_KERNEL(qkv_ab_nomfma, 4,  1, 1, 0)   // scratch: no MFMA (reads kept live via asm)
QKV_KERNEL(qkv_ab_skel,  12,  0, 0, 0)   // scratch: barriers + loop skeleton only

// ---------------- flash attention: 2x2 wave partition, S^T trick, dbuf DMA ----------------
__global__ __launch_bounds__(256) void attn_k(const unsigned short* __restrict__ Q,
                                              const unsigned short* __restrict__ K,
                                              const unsigned short* __restrict__ Vt,
                                              unsigned short* __restrict__ Om) {
    __shared__ __align__(16) unsigned short SM[20480];
    unsigned short* Ks0 = SM;
    unsigned short* Vts0 = SM + 8192;
    unsigned short* QP = SM + 16384;

    const int tid = threadIdx.x;
    const int w = tid >> 6, l = tid & 63, l15 = l & 15, quad = l >> 4;
    const int wq = w >> 1, ws = w & 1;
    const int bid = blockIdx.x;
    const int qt = 31 - (bid >> 5);
    const int hb = bid & 31;
    const int q0 = qt * 64;
    const unsigned short* Qb = Q + (size_t)hb * 131072;
    const unsigned short* Kb = K + (size_t)hb * 131072;
    const unsigned short* Vb = Vt + (size_t)hb * 131072;

    const int sr = w * 8 + (l >> 3);
    const int gch = (l & 7) ^ (l >> 3);
    const int swz7 = l15 & 7;

    load_lds16(Qb + (q0 + sr) * 64 + gch * 8, &QP[tid * 8]);
    load_lds16(Qb + (q0 + 32 + sr) * 64 + gch * 8, &QP[2048 + tid * 8]);
    load_lds16(Kb + sr * 64 + gch * 8, &Ks0[tid * 8]);
    load_lds16(Kb + (32 + sr) * 64 + gch * 8, &Ks0[2048 + tid * 8]);
    load_lds16(Vb + sr * 2048 + gch * 8, &Vts0[tid * 8]);
    load_lds16(Vb + (32 + sr) * 2048 + gch * 8, &Vts0[2048 + tid * 8]);
    __syncthreads();

    short8 qf[2][2];
#pragma unroll
    for (int qnt = 0; qnt < 2; qnt++)
#pragma unroll
        for (int ks = 0; ks < 2; ks++)
            qf[qnt][ks] = *(const short8*)&QP[(wq * 32 + qnt * 16 + l15) * 64 + (((ks * 4 + quad) ^ swz7) << 3)];

    short8 ones;
#pragma unroll
    for (int j = 0; j < 8; j++) ones[j] = (short)0x3F80;

    f32x4 o[2][4], lacc[2];
#pragma unroll
    for (int pmt = 0; pmt < 2; pmt++) {
        lacc[pmt] = (f32x4){0.f, 0.f, 0.f, 0.f};
#pragma unroll
        for (int dnt = 0; dnt < 4; dnt++) o[pmt][dnt] = (f32x4){0.f, 0.f, 0.f, 0.f};
    }

    for (int kt = 0; kt <= qt; kt++) {
        const int c = kt & 1;
        const unsigned short* Ksc = Ks0 + c * 4096;
        const unsigned short* Vtsc = Vts0 + c * 4096;
        __syncthreads();
        if (kt < qt) {
            const int kn = (kt + 1) * 64, pc = 1 - c;
            load_lds16(Kb + (kn + sr) * 64 + gch * 8, &Ks0[pc * 4096 + tid * 8]);
            load_lds16(Kb + (kn + 32 + sr) * 64 + gch * 8, &Ks0[pc * 4096 + 2048 + tid * 8]);
            load_lds16(Vb + sr * 2048 + kn + gch * 8, &Vts0[pc * 4096 + tid * 8]);
            load_lds16(Vb + (32 + sr) * 2048 + kn + gch * 8, &Vts0[pc * 4096 + 2048 + tid * 8]);
        }

        f32x4 sa[2][2];
#pragma unroll
        for (int smt = 0; smt < 2; smt++)
#pragma unroll
            for (int qnt = 0; qnt < 2; qnt++) sa[smt][qnt] = (f32x4){0.f, 0.f, 0.f, 0.f};
#pragma unroll
        for (int ks = 0; ks < 2; ks++) {
            short8 kf[2];
#pragma unroll
            for (int smt = 0; smt < 2; smt++)
                kf[smt] = *(const short8*)&Ksc[(ws * 32 + smt * 16 + l15) * 64 + (((ks * 4 + quad) ^ swz7) << 3)];
#pragma unroll
            for (int smt = 0; smt < 2; smt++)
#pragma unroll
                for (int qnt = 0; qnt < 2; qnt++)
                    sa[smt][qnt] = __builtin_amdgcn_mfma_f32_16x16x32_bf16(kf[smt], qf[qnt][ks], sa[smt][qnt], 0, 0, 0);
        }

        float pv[2][2][4];
        if (kt == qt) {
#pragma unroll
            for (int smt = 0; smt < 2; smt++)
#pragma unroll
                for (int qnt = 0; qnt < 2; qnt++)
#pragma unroll
                    for (int r = 0; r < 4; r++) {
                        int cg = kt * 64 + ws * 32 + smt * 16 + quad * 4 + r;
                        int rg = q0 + wq * 32 + qnt * 16 + l15;
                        pv[smt][qnt][r] = (cg <= rg) ? __expf(sa[smt][qnt][r]) : 0.f;
                    }
        } else {
#pragma unroll
            for (int smt = 0; smt < 2; smt++)
#pragma unroll
                for (int qnt = 0; qnt < 2; qnt++)
#pragma unroll
                    for (int r = 0; r < 4; r++)
                        pv[smt][qnt][r] = __expf(sa[smt][qnt][r]);
        }

#pragma unroll
        for (int smt = 0; smt < 2; smt++)
#pragma unroll
            for (int qnt = 0; qnt < 2; qnt++) {
                int q = wq * 32 + qnt * 16 + l15;
                int sb = ws * 32 + smt * 16 + quad * 4;
                int chp = (sb >> 3) ^ (q & 7);
                int a16 = q * 64 + (chp << 3) + (sb & 7);
                uint2 u;
                u.x = pk2(pv[smt][qnt][0], pv[smt][qnt][1]);
                u.y = pk2(pv[smt][qnt][2], pv[smt][qnt][3]);
                *(uint2*)&QP[a16] = u;
            }
    asm volatile("s_waitcnt lgkmcnt(0)" ::: "memory");

        short8 pf[2];
#pragma unroll
        for (int pmt = 0; pmt < 2; pmt++) {
            pf[pmt] = *(const short8*)&QP[(wq * 32 + pmt * 16 + l15) * 64 + (((ws * 4 + quad) ^ swz7) << 3)];
            lacc[pmt] = __builtin_amdgcn_mfma_f32_16x16x32_bf16(pf[pmt], ones, lacc[pmt], 0, 0, 0);
        }
#pragma unroll
        for (int dnt = 0; dnt < 4; dnt++) {
            short8 vf = *(const short8*)&Vtsc[(dnt * 16 + l15) * 64 + (((ws * 4 + quad) ^ swz7) << 3)];
#pragma unroll
            for (int pmt = 0; pmt < 2; pmt++)
                o[pmt][dnt] = __builtin_amdgcn_mfma_f32_16x16x32_bf16(pf[pmt], vf, o[pmt][dnt], 0, 0, 0);
        }
    }

    __syncthreads();
    float* red = (float*)SM;
    float* myp = red + (wq * 64 + l) * 41;
    if (ws == 1) {
#pragma unroll
        for (int pmt = 0; pmt < 2; pmt++) {
#pragma unroll
            for (int dnt = 0; dnt < 4; dnt++)
#pragma unroll
                for (int r = 0; r < 4; r++) myp[pmt * 16 + dnt * 4 + r] = o[pmt][dnt][r];
#pragma unroll
            for (int r = 0; r < 4; r++) myp[32 + pmt * 4 + r] = lacc[pmt][r];
        }
    }
    __syncthreads();
    if (ws == 0) {
        float inv[2][4];
#pragma unroll
        for (int pmt = 0; pmt < 2; pmt++)
#pragma unroll
            for (int r = 0; r < 4; r++)
                inv[pmt][r] = 1.0f / (lacc[pmt][r] + myp[32 + pmt * 4 + r]);
        const int b = hb >> 4, h = hb & 15;
#pragma unroll
        for (int pmt = 0; pmt < 2; pmt++)
#pragma unroll
            for (int dnt = 0; dnt < 4; dnt++)
#pragma unroll
                for (int r = 0; r < 4; r++) {
                    float val = (o[pmt][dnt][r] + myp[pmt * 16 + dnt * 4 + r]) * inv[pmt][r];
                    int sg = q0 + wq * 32 + pmt * 16 + quad * 4 + r;
                    int col = h * 64 + dnt * 16 + l15;
                    Om[((size_t)(b * 2048 + sg)) * 1024 + col] = f2b(val);
                }
    }
}

// ---------------- proj GEMM 128x64, dbuf DMA, fp32 out ----------------
__global__ __launch_bounds__(256) void proj_gemm(const unsigned short* __restrict__ A,
                                                 const unsigned short* __restrict__ WT,
                                                 const float* __restrict__ bias,
                                                 float* __restrict__ out) {
    __shared__ __align__(16) unsigned short As[2][4096];
    __shared__ __align__(16) unsigned short Bs[2][2048];
    const int tid = threadIdx.x;
    const int w = tid >> 6, l = tid & 63, l15 = l & 15, quad = l >> 4;
    const int wr = w >> 1, wc = w & 1;
    const int m0 = blockIdx.y * 128, n0 = blockIdx.x * 64;

    const int sr = w * 16 + (l >> 2);
    const int gch = (l & 3) ^ ((l >> 3) & 3);
    const unsigned short* Asrc = A + (size_t)(m0 + sr) * 1024 + gch * 8;
    const unsigned short* Bsrc = WT + (size_t)(n0 + sr) * 1024 + gch * 8;
    const int rswz = (l15 >> 1) & 3;

    f32x4 acc[4][2];
#pragma unroll
    for (int mt = 0; mt < 4; mt++)
#pragma unroll
        for (int nt = 0; nt < 2; nt++) acc[mt][nt] = (f32x4){0.f, 0.f, 0.f, 0.f};

    load_lds16(Asrc, &As[0][tid * 8]);
    load_lds16(Asrc + 65536, &As[0][2048 + tid * 8]);
    load_lds16(Bsrc, &Bs[0][tid * 8]);

    for (int k0 = 0; k0 < 1024; k0 += 32) {
        const int c = (k0 >> 5) & 1;
        __syncthreads();
        if (k0 + 32 < 1024) {
            const int pc = 1 - c;
            load_lds16(Asrc + k0 + 32, &As[pc][tid * 8]);
            load_lds16(Asrc + 65536 + k0 + 32, &As[pc][2048 + tid * 8]);
            load_lds16(Bsrc + k0 + 32, &Bs[pc][tid * 8]);
        }

        short8 af[4], bfr[2];
#pragma unroll
        for (int mt = 0; mt < 4; mt++)
            af[mt] = *(const short8*)&As[c][(wr * 64 + mt * 16 + l15) * 32 + ((quad ^ rswz) * 8)];
#pragma unroll
        for (int nt = 0; nt < 2; nt++)
            bfr[nt] = *(const short8*)&Bs[c][(wc * 32 + nt * 16 + l15) * 32 + ((quad ^ rswz) * 8)];
#pragma unroll
        for (int mt = 0; mt < 4; mt++)
#pragma unroll
            for (int nt = 0; nt < 2; nt++)
                acc[mt][nt] = __builtin_amdgcn_mfma_f32_16x16x32_bf16(af[mt], bfr[nt], acc[mt][nt], 0, 0, 0);
    }

#pragma unroll
    for (int mt = 0; mt < 4; mt++)
#pragma unroll
        for (int nt = 0; nt < 2; nt++)
#pragma unroll
            for (int r = 0; r < 4; r++) {
                int mg = m0 + wr * 64 + mt * 16 + quad * 4 + r;
                int ng = n0 + wc * 32 + nt * 16 + l15;
                out[(size_t)mg * 1024 + ng] = acc[mt][nt][r] + bias[ng];
            }
}

extern "C" void kernel_launch(void* const* d_in, const int* in_sizes, int n_in,
                              void* d_out, int out_size, void* d_ws, size_t ws_size,
                              hipStream_t stream) {
    (void)in_sizes; (void)n_in; (void)out_size; (void)ws_size;
    const float* x      = (const float*)d_in[0];
    const float* w_attn = (const float*)d_in[1];
    const float* b_attn = (const float*)d_in[2];
    const float* w_proj = (const float*)d_in[3];
    const float* b_proj = (const float*)d_in[4];
    float* out = (float*)d_out;
    unsigned short* ws = (unsigned short*)d_ws;

    unsigned short* wtA  = ws;                     // 3072*1024 (head-permuted rows)
    unsigned short* wtP  = wtA + 3145728;          // 1024*1024
    unsigned short* Qw   = wtP + 1048576;          // [B*H][2048][64]
    unsigned short* Kw   = Qw + 4194304;           // [B*H][2048][64] (pre-scaled 1/8)
    unsigned short* Vtw  = Kw + 4194304;           // [B*H][64][2048] (V^T)
    unsigned short* XbOm = Vtw + 4194304;          // X bf16, later attn-out
    // ablation scratch (garbage outputs; ~25 MB beyond live region)
    unsigned short* scrQ = XbOm + 4194304;
    unsigned short* scrK = scrQ + 4194304;
    unsigned short* scrV = scrK + 4194304;

    prep<<<8192, 256, 0, stream>>>(x, (unsigned int*)XbOm, w_attn, wtA, w_proj, wtP);
    qkv_gemm<<<dim3(16, 32), 256, 0, stream>>>(XbOm, wtA, b_attn, Qw, Kw, Vtw);
    // ablation sweep (scratch outputs, distinct kernel names -> per-name rocprof rows)
    qkv_ab_full  <<<dim3(16, 32), 256, 0, stream>>>(XbOm, wtA, b_attn, scrQ, scrK, scrV);
    qkv_ab_nodma <<<dim3(16, 32), 256, 0, stream>>>(XbOm, wtA, b_attn, scrQ, scrK, scrV);
    qkv_ab_nordd <<<dim3(16, 32), 256, 0, stream>>>(XbOm, wtA, b_attn, scrQ, scrK, scrV);
    qkv_ab_nomfma<<<dim3(16, 32), 256, 0, stream>>>(XbOm, wtA, b_attn, scrQ, scrK, scrV);
    qkv_ab_skel  <<<dim3(16, 32), 256, 0, stream>>>(XbOm, wtA, b_attn, scrQ, scrK, scrV);
    attn_k<<<1024, 256, 0, stream>>>(Qw, Kw, Vtw, XbOm);
    proj_gemm<<<dim3(16, 32), 256, 0, stream>>>(XbOm, wtP, b_proj, out);
}

// Round 10
// 436.700 us; speedup vs baseline: 1.6054x; 1.6054x over previous
//
#include <hip/hip_runtime.h>
#include <hip/hip_bf16.h>

// R10: pivot to attn (qkv plateaued at ~600 TF across 6 structures; R9 ablation shows
// latency-chain, no dominant phase). attn change: DROP V LDS staging (m169: +26% — V^T
// is 256KB/head, L2-fit; staging was pure overhead). PV reads vf directly from global,
// hoisted after the K-barrier so QK^T+softmax hides L2 latency. Bit-identical output.
// qkv = clean R7 (best measured, 43us). ATTN_REP=8 instrumentation -> attn claims top-5.

#define ATTN_REP 8

typedef short short8 __attribute__((ext_vector_type(8)));
typedef float f32x4 __attribute__((ext_vector_type(4)));

__device__ __forceinline__ unsigned short f2b(float f) {
    unsigned int x;
    __builtin_memcpy(&x, &f, 4);
    unsigned int r = x + 0x7FFF + ((x >> 16) & 1);  // RNE
    return (unsigned short)(r >> 16);
}

__device__ __forceinline__ unsigned int pk2(float a, float b) {
    __hip_bfloat162 h = __float22bfloat162_rn(make_float2(a, b));
    unsigned int u;
    __builtin_memcpy(&u, &h, 4);
    return u;
}

__device__ __forceinline__ void load_lds16(const unsigned short* g, unsigned short* l) {
    __builtin_amdgcn_global_load_lds(
        (const __attribute__((address_space(1))) unsigned int*)g,
        (__attribute__((address_space(3))) unsigned int*)l, 16, 0, 0);
}

// ---------------- prep: xcast (blocks 0..4095) + W transposes ----------------
// wtA rows PERMUTED: row = h*192 + type*64 + d  (type=c>>10, h=(c>>6)&15, d=c&63)
__global__ __launch_bounds__(256) void prep(const float* __restrict__ x, unsigned int* __restrict__ xb,
                                            const float* __restrict__ wA, unsigned short* __restrict__ wtA,
                                            const float* __restrict__ wP, unsigned short* __restrict__ wtP) {
    const int bx = blockIdx.x, tid = threadIdx.x;
    if (bx < 4096) {
        int i = (bx * 256 + tid) * 4;
        float4 f = *(const float4*)(x + i);
        uint2 p;
        p.x = (unsigned int)f2b(f.x) | ((unsigned int)f2b(f.y) << 16);
        p.y = (unsigned int)f2b(f.z) | ((unsigned int)f2b(f.w) << 16);
        *(uint2*)(xb + i / 2) = p;
        return;
    }
    __shared__ unsigned short t[32][33];
    const float* in;
    unsigned short* out;
    int R, C, gx, gy, oc0;
    if (bx < 7168) {
        int i = bx - 4096; gx = i % 96; gy = i / 96; in = wA; out = wtA; R = 1024; C = 3072;
        int c0 = gx * 32;
        oc0 = ((c0 >> 6) & 15) * 192 + (c0 >> 10) * 64 + (c0 & 63);
    } else {
        int i = bx - 7168; gx = i % 32; gy = i / 32; in = wP; out = wtP; R = 1024; C = 1024;
        oc0 = gx * 32;
    }
    const int tx = tid & 31, ty = tid >> 5;
    const int c0 = gx * 32, r0 = gy * 32;
#pragma unroll
    for (int i = 0; i < 4; i++)
        t[ty + i * 8][tx] = f2b(in[(r0 + ty + i * 8) * C + c0 + tx]);
    __syncthreads();
#pragma unroll
    for (int i = 0; i < 4; i++)
        out[(oc0 + ty + i * 8) * R + r0 + tx] = t[tx][ty + i * 8];
}

// ---------------- QKV GEMM: 128x192, BK=32, ring-4, dist-3 prefetch (R7, best measured) ----------------
__global__ __launch_bounds__(256, 2) void qkv_gemm(const unsigned short* __restrict__ X,
                                                   const unsigned short* __restrict__ WT,
                                                   const float* __restrict__ bias,
                                                   unsigned short* __restrict__ Qo,
                                                   unsigned short* __restrict__ Ko,
                                                   unsigned short* __restrict__ Vt) {
    __shared__ __align__(16) unsigned short SM[40960];  // Al 16384 | Bl 24576 = 80KB
    unsigned short* Al = SM;
    unsigned short* Bl = SM + 16384;

    const int tid = threadIdx.x;
    const int w = tid >> 6, l = tid & 63, l15 = l & 15, quad = l >> 4;
    const int wm = w >> 1, wn = w & 1;

    const int fid = blockIdx.x + (blockIdx.y << 4);
    const int xcd = fid & 7, j8 = fid >> 3;
    const int by = ((xcd >> 1) << 3) + (j8 >> 3);
    const int bx = ((xcd & 1) << 3) + (j8 & 7);
    const int m0 = by * 128, n0 = bx * 192, hx = bx;

    const int trow = tid >> 2;
    const int ch = (tid & 3) ^ ((tid >> 3) & 3);
    const unsigned short* Asrc = X + (size_t)(m0 + trow) * 1024 + ch * 8;
    const unsigned short* Bsrc = WT + (size_t)(n0 + trow) * 1024 + ch * 8;

    const int koff = (quad ^ ((l15 >> 1) & 3)) << 3;

    auto stageA = [&](int buf, int k0) {
#pragma unroll
        for (int u = 0; u < 2; ++u)
            load_lds16(Asrc + u * 65536 + k0, Al + buf * 4096 + u * 2048 + tid * 8);
    };
    auto stageB = [&](int buf, int k0) {
#pragma unroll
        for (int u = 0; u < 3; ++u)
            load_lds16(Bsrc + u * 65536 + k0, Bl + buf * 6144 + u * 2048 + tid * 8);
    };

    const int b = m0 >> 11, sbase = m0 & 2047;

    short8 af[4], bf[6];
    f32x4 acc[4][6];
#pragma unroll
    for (int mt = 0; mt < 4; ++mt)
#pragma unroll
        for (int nt = 0; nt < 6; ++nt) acc[mt][nt] = (f32x4){0.f, 0.f, 0.f, 0.f};

    stageA(0, 0); stageB(0, 0);
    stageA(1, 32); stageB(1, 32);
    stageA(2, 64); stageB(2, 64);

#pragma unroll 1
    for (int t = 0; t < 32; ++t) {
        const int c = t & 3;
        asm volatile("s_barrier" ::: "memory");
        if (t < 29) {
            const int kn = (t + 3) * 32;
            stageA((t + 3) & 3, kn);
            stageB((t + 3) & 3, kn);
            asm volatile("s_waitcnt vmcnt(15)" ::: "memory");
        } else if (t == 29) {
            asm volatile("s_waitcnt vmcnt(10)" ::: "memory");
        } else if (t == 30) {
            asm volatile("s_waitcnt vmcnt(5)" ::: "memory");
        } else {
            asm volatile("s_waitcnt vmcnt(0)" ::: "memory");
        }
        const unsigned short* Ab = Al + c * 4096 + (wm * 64 + l15) * 32 + koff;
        const unsigned short* Bb = Bl + c * 6144 + (wn * 96 + l15) * 32 + koff;
#pragma unroll
        for (int mt = 0; mt < 4; ++mt) af[mt] = *(const short8*)(Ab + mt * 512);
#pragma unroll
        for (int nt = 0; nt < 6; ++nt) bf[nt] = *(const short8*)(Bb + nt * 512);
        asm volatile("s_waitcnt lgkmcnt(0)" ::: "memory");
        __builtin_amdgcn_sched_barrier(0);
        __builtin_amdgcn_s_setprio(1);
#pragma unroll
        for (int mt = 0; mt < 4; ++mt)
#pragma unroll
            for (int nt = 0; nt < 6; ++nt)
                acc[mt][nt] = __builtin_amdgcn_mfma_f32_16x16x32_bf16(af[mt], bf[nt], acc[mt][nt], 0, 0, 0);
        __builtin_amdgcn_s_setprio(0);
    }
    __syncthreads();

#pragma unroll
    for (int nt = 0; nt < 6; ++nt) {
        const int f = wn * 96 + nt * 16;
        const int type = f >> 6, d0 = f & 63;
        const float bvv = bias[type * 1024 + hx * 64 + d0 + l15];
        if (type < 2) {
            const float scale = type ? 0.125f : 1.0f;
            unsigned short* dst = type ? Ko : Qo;
#pragma unroll
            for (int mt = 0; mt < 4; ++mt)
#pragma unroll
                for (int r = 0; r < 4; ++r) {
                    int m = m0 + wm * 64 + mt * 16 + quad * 4 + r;
                    dst[(((size_t)(b * 16 + hx)) * 2048 + (m & 2047)) * 64 + d0 + l15] =
                        f2b((acc[mt][nt][r] + bvv) * scale);
                }
        } else {
            const int d = d0 + l15;
#pragma unroll
            for (int mt = 0; mt < 4; ++mt) {
                int mloc = wm * 64 + mt * 16 + quad * 4;
                uint2 u;
                u.x = pk2(acc[mt][nt][0] + bvv, acc[mt][nt][1] + bvv);
                u.y = pk2(acc[mt][nt][2] + bvv, acc[mt][nt][3] + bvv);
                *(uint2*)&SM[d * 136 + mloc] = u;
            }
        }
    }
    __syncthreads();
    {
        const int d = tid >> 2, mseg = (tid & 3) * 32;
        size_t gb = ((size_t)((b * 16 + hx) * 64 + d)) * 2048 + sbase + mseg;
#pragma unroll
        for (int q = 0; q < 4; ++q)
            *(uint4*)(Vt + gb + q * 8) = *(const uint4*)&SM[d * 136 + mseg + q * 8];
    }
}

// ---------------- flash attention: 2x2 wave partition, S^T trick ----------------
// V NOT staged in LDS (L2-fit, m169): vf read direct from global V^T, hoisted after the
// K-barrier so QK^T+softmax hides L2 latency. K double-buffered in LDS as before.
__global__ __launch_bounds__(256) void attn_k(const unsigned short* __restrict__ Q,
                                              const unsigned short* __restrict__ K,
                                              const unsigned short* __restrict__ Vt,
                                              unsigned short* __restrict__ Om) {
    __shared__ __align__(16) unsigned short SM[12288];  // Ks[2][4096] | QP[4096] = 24KB
    unsigned short* Ks0 = SM;
    unsigned short* QP = SM + 8192;

    const int tid = threadIdx.x;
    const int w = tid >> 6, l = tid & 63, l15 = l & 15, quad = l >> 4;
    const int wq = w >> 1, ws = w & 1;
    const int bid = blockIdx.x;
    const int qt = 31 - (bid >> 5);
    const int hb = bid & 31;
    const int q0 = qt * 64;
    const unsigned short* Qb = Q + (size_t)hb * 131072;
    const unsigned short* Kb = K + (size_t)hb * 131072;
    const unsigned short* Vb = Vt + (size_t)hb * 131072;

    const int sr = w * 8 + (l >> 3);
    const int gch = (l & 7) ^ (l >> 3);
    const int swz7 = l15 & 7;
    const int vchunk = (ws * 4 + quad) * 8;   // vf k-chunk within the 64-col tile (shorts)

    short8 ones;
#pragma unroll
    for (int j = 0; j < 8; j++) ones[j] = (short)0x3F80;

    for (int rep = 0; rep < ATTN_REP; ++rep) {
        // prologue: stage Q + K tile 0
        load_lds16(Qb + (q0 + sr) * 64 + gch * 8, &QP[tid * 8]);
        load_lds16(Qb + (q0 + 32 + sr) * 64 + gch * 8, &QP[2048 + tid * 8]);
        load_lds16(Kb + sr * 64 + gch * 8, &Ks0[tid * 8]);
        load_lds16(Kb + (32 + sr) * 64 + gch * 8, &Ks0[2048 + tid * 8]);
        __syncthreads();

        short8 qf[2][2];
#pragma unroll
        for (int qnt = 0; qnt < 2; qnt++)
#pragma unroll
            for (int ks = 0; ks < 2; ks++)
                qf[qnt][ks] = *(const short8*)&QP[(wq * 32 + qnt * 16 + l15) * 64 + (((ks * 4 + quad) ^ swz7) << 3)];

        f32x4 o[2][4], lacc[2];
#pragma unroll
        for (int pmt = 0; pmt < 2; pmt++) {
            lacc[pmt] = (f32x4){0.f, 0.f, 0.f, 0.f};
#pragma unroll
            for (int dnt = 0; dnt < 4; dnt++) o[pmt][dnt] = (f32x4){0.f, 0.f, 0.f, 0.f};
        }

        for (int kt = 0; kt <= qt; kt++) {
            const int c = kt & 1;
            const unsigned short* Ksc = Ks0 + c * 4096;
            __syncthreads();  // K buf c's DMA drained
            if (kt < qt) {
                const int kn = (kt + 1) * 64, pc = 1 - c;
                load_lds16(Kb + (kn + sr) * 64 + gch * 8, &Ks0[pc * 4096 + tid * 8]);
                load_lds16(Kb + (kn + 32 + sr) * 64 + gch * 8, &Ks0[pc * 4096 + 2048 + tid * 8]);
            }

            // hoisted V fragments from global (L2-hot); latency hidden under QK^T+softmax
            short8 vf[4];
#pragma unroll
            for (int dnt = 0; dnt < 4; dnt++)
                vf[dnt] = *(const short8*)(Vb + (size_t)(dnt * 16 + l15) * 2048 + kt * 64 + vchunk);

            // S^T = K @ Q^T
            f32x4 sa[2][2];
#pragma unroll
            for (int smt = 0; smt < 2; smt++)
#pragma unroll
                for (int qnt = 0; qnt < 2; qnt++) sa[smt][qnt] = (f32x4){0.f, 0.f, 0.f, 0.f};
#pragma unroll
            for (int ks = 0; ks < 2; ks++) {
                short8 kf[2];
#pragma unroll
                for (int smt = 0; smt < 2; smt++)
                    kf[smt] = *(const short8*)&Ksc[(ws * 32 + smt * 16 + l15) * 64 + (((ks * 4 + quad) ^ swz7) << 3)];
#pragma unroll
                for (int smt = 0; smt < 2; smt++)
#pragma unroll
                    for (int qnt = 0; qnt < 2; qnt++)
                        sa[smt][qnt] = __builtin_amdgcn_mfma_f32_16x16x32_bf16(kf[smt], qf[qnt][ks], sa[smt][qnt], 0, 0, 0);
            }

            float pv[2][2][4];
            if (kt == qt) {
#pragma unroll
                for (int smt = 0; smt < 2; smt++)
#pragma unroll
                    for (int qnt = 0; qnt < 2; qnt++)
#pragma unroll
                        for (int r = 0; r < 4; r++) {
                            int cg = kt * 64 + ws * 32 + smt * 16 + quad * 4 + r;
                            int rg = q0 + wq * 32 + qnt * 16 + l15;
                            pv[smt][qnt][r] = (cg <= rg) ? __expf(sa[smt][qnt][r]) : 0.f;
                        }
            } else {
#pragma unroll
                for (int smt = 0; smt < 2; smt++)
#pragma unroll
                    for (int qnt = 0; qnt < 2; qnt++)
#pragma unroll
                        for (int r = 0; r < 4; r++)
                            pv[smt][qnt][r] = __expf(sa[smt][qnt][r]);
            }

#pragma unroll
            for (int smt = 0; smt < 2; smt++)
#pragma unroll
                for (int qnt = 0; qnt < 2; qnt++) {
                    int q = wq * 32 + qnt * 16 + l15;
                    int sb = ws * 32 + smt * 16 + quad * 4;
                    int chp = (sb >> 3) ^ (q & 7);
                    int a16 = q * 64 + (chp << 3) + (sb & 7);
                    uint2 u;
                    u.x = pk2(pv[smt][qnt][0], pv[smt][qnt][1]);
                    u.y = pk2(pv[smt][qnt][2], pv[smt][qnt][3]);
                    *(uint2*)&QP[a16] = u;
                }
            asm volatile("s_waitcnt lgkmcnt(0)" ::: "memory");  // wave-local P visible

            short8 pf[2];
#pragma unroll
            for (int pmt = 0; pmt < 2; pmt++) {
                pf[pmt] = *(const short8*)&QP[(wq * 32 + pmt * 16 + l15) * 64 + (((ws * 4 + quad) ^ swz7) << 3)];
                lacc[pmt] = __builtin_amdgcn_mfma_f32_16x16x32_bf16(pf[pmt], ones, lacc[pmt], 0, 0, 0);
            }
#pragma unroll
            for (int dnt = 0; dnt < 4; dnt++)
#pragma unroll
                for (int pmt = 0; pmt < 2; pmt++)
                    o[pmt][dnt] = __builtin_amdgcn_mfma_f32_16x16x32_bf16(pf[pmt], vf[dnt], o[pmt][dnt], 0, 0, 0);
        }

        __syncthreads();
        float* red = (float*)SM;
        float* myp = red + (wq * 64 + l) * 41;
        if (ws == 1) {
#pragma unroll
            for (int pmt = 0; pmt < 2; pmt++) {
#pragma unroll
                for (int dnt = 0; dnt < 4; dnt++)
#pragma unroll
                    for (int r = 0; r < 4; r++) myp[pmt * 16 + dnt * 4 + r] = o[pmt][dnt][r];
#pragma unroll
                for (int r = 0; r < 4; r++) myp[32 + pmt * 4 + r] = lacc[pmt][r];
            }
        }
        __syncthreads();
        if (ws == 0) {
            float inv[2][4];
#pragma unroll
            for (int pmt = 0; pmt < 2; pmt++)
#pragma unroll
                for (int r = 0; r < 4; r++)
                    inv[pmt][r] = 1.0f / (lacc[pmt][r] + myp[32 + pmt * 4 + r]);
            const int b = hb >> 4, h = hb & 15;
#pragma unroll
            for (int pmt = 0; pmt < 2; pmt++)
#pragma unroll
                for (int dnt = 0; dnt < 4; dnt++)
#pragma unroll
                    for (int r = 0; r < 4; r++) {
                        float val = (o[pmt][dnt][r] + myp[pmt * 16 + dnt * 4 + r]) * inv[pmt][r];
                        int sg = q0 + wq * 32 + pmt * 16 + quad * 4 + r;
                        int col = h * 64 + dnt * 16 + l15;
                        Om[((size_t)(b * 2048 + sg)) * 1024 + col] = f2b(val);
                    }
        }
        __syncthreads();  // rep seam
    }
}

// ---------------- proj GEMM 128x64, dbuf DMA, fp32 out ----------------
__global__ __launch_bounds__(256) void proj_gemm(const unsigned short* __restrict__ A,
                                                 const unsigned short* __restrict__ WT,
                                                 const float* __restrict__ bias,
                                                 float* __restrict__ out) {
    __shared__ __align__(16) unsigned short As[2][4096];
    __shared__ __align__(16) unsigned short Bs[2][2048];
    const int tid = threadIdx.x;
    const int w = tid >> 6, l = tid & 63, l15 = l & 15, quad = l >> 4;
    const int wr = w >> 1, wc = w & 1;
    const int m0 = blockIdx.y * 128, n0 = blockIdx.x * 64;

    const int sr = w * 16 + (l >> 2);
    const int gch = (l & 3) ^ ((l >> 3) & 3);
    const unsigned short* Asrc = A + (size_t)(m0 + sr) * 1024 + gch * 8;
    const unsigned short* Bsrc = WT + (size_t)(n0 + sr) * 1024 + gch * 8;
    const int rswz = (l15 >> 1) & 3;

    f32x4 acc[4][2];
#pragma unroll
    for (int mt = 0; mt < 4; mt++)
#pragma unroll
        for (int nt = 0; nt < 2; nt++) acc[mt][nt] = (f32x4){0.f, 0.f, 0.f, 0.f};

    load_lds16(Asrc, &As[0][tid * 8]);
    load_lds16(Asrc + 65536, &As[0][2048 + tid * 8]);
    load_lds16(Bsrc, &Bs[0][tid * 8]);

    for (int k0 = 0; k0 < 1024; k0 += 32) {
        const int c = (k0 >> 5) & 1;
        __syncthreads();
        if (k0 + 32 < 1024) {
            const int pc = 1 - c;
            load_lds16(Asrc + k0 + 32, &As[pc][tid * 8]);
            load_lds16(Asrc + 65536 + k0 + 32, &As[pc][2048 + tid * 8]);
            load_lds16(Bsrc + k0 + 32, &Bs[pc][tid * 8]);
        }

        short8 af[4], bfr[2];
#pragma unroll
        for (int mt = 0; mt < 4; mt++)
            af[mt] = *(const short8*)&As[c][(wr * 64 + mt * 16 + l15) * 32 + ((quad ^ rswz) * 8)];
#pragma unroll
        for (int nt = 0; nt < 2; nt++)
            bfr[nt] = *(const short8*)&Bs[c][(wc * 32 + nt * 16 + l15) * 32 + ((quad ^ rswz) * 8)];
#pragma unroll
        for (int mt = 0; mt < 4; mt++)
#pragma unroll
            for (int nt = 0; nt < 2; nt++)
                acc[mt][nt] = __builtin_amdgcn_mfma_f32_16x16x32_bf16(af[mt], bfr[nt], acc[mt][nt], 0, 0, 0);
    }

#pragma unroll
    for (int mt = 0; mt < 4; mt++)
#pragma unroll
        for (int nt = 0; nt < 2; nt++)
#pragma unroll
            for (int r = 0; r < 4; r++) {
                int mg = m0 + wr * 64 + mt * 16 + quad * 4 + r;
                int ng = n0 + wc * 32 + nt * 16 + l15;
                out[(size_t)mg * 1024 + ng] = acc[mt][nt][r] + bias[ng];
            }
}

extern "C" void kernel_launch(void* const* d_in, const int* in_sizes, int n_in,
                              void* d_out, int out_size, void* d_ws, size_t ws_size,
                              hipStream_t stream) {
    (void)in_sizes; (void)n_in; (void)out_size; (void)ws_size;
    const float* x      = (const float*)d_in[0];
    const float* w_attn = (const float*)d_in[1];
    const float* b_attn = (const float*)d_in[2];
    const float* w_proj = (const float*)d_in[3];
    const float* b_proj = (const float*)d_in[4];
    float* out = (float*)d_out;
    unsigned short* ws = (unsigned short*)d_ws;

    unsigned short* wtA  = ws;                     // 3072*1024 (head-permuted rows)
    unsigned short* wtP  = wtA + 3145728;          // 1024*1024
    unsigned short* Qw   = wtP + 1048576;          // [B*H][2048][64]
    unsigned short* Kw   = Qw + 4194304;           // [B*H][2048][64] (pre-scaled 1/8)
    unsigned short* Vtw  = Kw + 4194304;           // [B*H][64][2048] (V^T)
    unsigned short* XbOm = Vtw + 4194304;          // X bf16, later attn-out

    prep<<<8192, 256, 0, stream>>>(x, (unsigned int*)XbOm, w_attn, wtA, w_proj, wtP);
    qkv_gemm<<<dim3(16, 32), 256, 0, stream>>>(XbOm, wtA, b_attn, Qw, Kw, Vtw);
    attn_k<<<1024, 256, 0, stream>>>(Qw, Kw, Vtw, XbOm);
    proj_gemm<<<dim3(16, 32), 256, 0, stream>>>(XbOm, wtP, b_proj, out);
}